// Round 1
// baseline (363.118 us; speedup 1.0000x reference)
//
#include <hip/hip_runtime.h>
#include <math.h>

// Problem constants (fixed by setup_inputs in the reference):
//   B=8, L=80000, D=128, K=1152 (read at runtime from d_in[5], clamped to KMAX).
// Algorithm: power[b,t,d] = b_mag_d^2 * |S|^2 where S obeys the one-pole
// complex recurrence S[t] = r_d*S[t-1] + x[b,t], r_d = e^{alpha_d} e^{i omega_d}.
// b_phase drops out of |H|^2. Chunked over t with K-step warm-up from zero
// state, which equals the reference's K-truncated FIR up to terms of
// amplitude <= e^{-11.52} ~ 1e-5 (negligible vs. threshold).

#define BB 8
#define LL 80000
#define DD 128
#define CHUNK 500
#define NCHUNK 160        // CHUNK * NCHUNK == LL exactly
#define KMAX 1152

__global__ __launch_bounds__(DD) void sstfr_kernel(
    const float* __restrict__ x,          // (B, L)
    const float* __restrict__ omega,      // (D,)
    const float* __restrict__ alpha_raw,  // (D,)
    const float* __restrict__ b_log_mag,  // (D,)
    const int*   __restrict__ Kp,         // scalar
    float*       __restrict__ out)        // (B, L, D)
{
    __shared__ float xs[CHUNK + KMAX];

    const int d     = threadIdx.x;     // channel, 0..127
    const int chunk = blockIdx.x;      // 0..NCHUNK-1
    const int b     = blockIdx.y;      // 0..B-1

    int K = Kp[0];
    if (K > KMAX) K = KMAX;            // deterministic K=1152; clamp for safety

    const int t0    = chunk * CHUNK;   // first output timestep of this chunk
    const int base  = t0 - K;          // first staged x index (may be negative)
    const int total = CHUNK + K;
    const float* xb = x + (size_t)b * LL;

    // Cooperative stage of x window into LDS (zero-pad out-of-range = left pad).
    for (int i = d; i < total; i += DD) {
        const int idx = base + i;
        xs[i] = (idx >= 0 && idx < LL) ? xb[idx] : 0.0f;
    }
    __syncthreads();

    // Per-channel filter parameters (computed once; use precise libm).
    const float w     = omega[d];
    const float alpha = -log1pf(expf(alpha_raw[d]));   // -softplus
    const float ea    = expf(alpha);
    const float er    = ea * cosf(w);
    const float ei    = ea * sinf(w);
    const float scale = expf(2.0f * b_log_mag[d]);     // b_mag^2

    float sr = 0.0f, si = 0.0f;

    // Warm-up: K steps, no output. Dependent chain = 2 FMAs/step.
    #pragma unroll 4
    for (int i = 0; i < K; ++i) {
        const float xv = xs[i];
        const float nr = fmaf(er, sr, fmaf(-ei, si, xv));
        const float ni = fmaf(er, si, ei * sr);
        sr = nr; si = ni;
    }

    // Output region: lanes d=0..127 write out[b, t, 0..127] -> coalesced.
    float* ob = out + ((size_t)b * LL + t0) * DD + d;
    #pragma unroll 4
    for (int j = 0; j < CHUNK; ++j) {
        const float xv = xs[K + j];
        const float nr = fmaf(er, sr, fmaf(-ei, si, xv));
        const float ni = fmaf(er, si, ei * sr);
        sr = nr; si = ni;
        ob[(size_t)j * DD] = scale * fmaf(sr, sr, si * si);
    }
}

extern "C" void kernel_launch(void* const* d_in, const int* in_sizes, int n_in,
                              void* d_out, int out_size, void* d_ws, size_t ws_size,
                              hipStream_t stream) {
    const float* x         = (const float*)d_in[0];
    const float* omega     = (const float*)d_in[1];
    const float* alpha_raw = (const float*)d_in[2];
    const float* b_log_mag = (const float*)d_in[3];
    // d_in[4] = b_phase: unused (cancels in |H|^2)
    const int*   Kp        = (const int*)d_in[5];
    float* out = (float*)d_out;

    dim3 grid(NCHUNK, BB);
    dim3 block(DD);
    sstfr_kernel<<<grid, block, 0, stream>>>(x, omega, alpha_raw, b_log_mag, Kp, out);
}

// Round 2
// 354.850 us; speedup vs baseline: 1.0233x; 1.0233x over previous
//
#include <hip/hip_runtime.h>
#include <math.h>

// power[b,t,d] = b_mag_d^2 * |S|^2,  S[t] = r_d*S[t-1] + x[b,t],
// r_d = e^{-softplus(alpha_raw_d)} * e^{i*omega_d}.  b_phase cancels in |H|^2.
// Chunked over t with K-step warm-up from zero state == reference's
// K-truncated FIR up to ~1e-5 amplitude terms.
//
// R1 change: LDS reads pipelined as float4 groups with one-group-ahead
// rotating prefetch so ds_read latency (~120 cyc) overlaps the dependent
// FMA chain instead of stalling it every step.

#define BB 8
#define LL 80000
#define DD 128
#define CHUNK 500         // multiple of 4; CHUNK * NCHUNK == LL
#define NCHUNK 160
#define KMAX 1152         // multiple of 4

#define STEP(xv)                                   \
    {                                              \
        float t1 = fmaf(-ei, si, (xv));            \
        float nr = fmaf(er, sr, t1);               \
        float ni = fmaf(er, si, ei * sr);          \
        sr = nr; si = ni;                          \
    }

__global__ __launch_bounds__(DD) void sstfr_kernel(
    const float* __restrict__ x,          // (B, L)
    const float* __restrict__ omega,      // (D,)
    const float* __restrict__ alpha_raw,  // (D,)
    const float* __restrict__ b_log_mag,  // (D,)
    const int*   __restrict__ Kp,         // scalar
    float*       __restrict__ out)        // (B, L, D)
{
    __shared__ __align__(16) float xs[KMAX + CHUNK];

    const int d     = threadIdx.x;     // channel, 0..127
    const int chunk = blockIdx.x;      // 0..NCHUNK-1
    const int b     = blockIdx.y;      // 0..B-1

    int K = Kp[0];
    K = (K + 3) & ~3;                  // round up to float4 granularity
    if (K > KMAX) K = KMAX;            // deterministic K=1152; clamp for safety

    const int t0    = chunk * CHUNK;
    const int base  = t0 - K;          // first staged x index (may be negative)
    const int total = CHUNK + K;
    const float* xb = x + (size_t)b * LL;

    // Stage x window into LDS (zero-pad the left edge).
    for (int i = d; i < total; i += DD) {
        const int idx = base + i;
        xs[i] = (idx >= 0 && idx < LL) ? xb[idx] : 0.0f;
    }
    __syncthreads();

    // Per-channel filter parameters.
    const float w     = omega[d];
    const float alpha = -log1pf(expf(alpha_raw[d]));   // -softplus
    const float ea    = expf(alpha);
    const float er    = ea * cosf(w);
    const float ei    = ea * sinf(w);
    const float scale = expf(2.0f * b_log_mag[d]);     // b_mag^2

    float sr = 0.0f, si = 0.0f;

    const float4* x4 = (const float4*)xs;
    const int g0 = K >> 2;                 // warm-up groups
    const int gT = total >> 2;             // total groups

    float4 cur = x4[0];

    // Warm-up: prefetch next group before consuming current.
    for (int q = 0; q < g0; ++q) {
        float4 nxt = x4[q + 1];            // q+1 <= g0 < gT: always valid
        STEP(cur.x) STEP(cur.y) STEP(cur.z) STEP(cur.w)
        cur = nxt;
    }

    // Output region: lanes write out[b, t, 0..127] -> coalesced 512B/step.
    float* op = out + ((size_t)b * LL + t0) * DD + d;
    for (int q = g0; q < gT - 1; ++q) {
        float4 nxt = x4[q + 1];
        STEP(cur.x) op[0 * DD] = scale * fmaf(sr, sr, si * si);
        STEP(cur.y) op[1 * DD] = scale * fmaf(sr, sr, si * si);
        STEP(cur.z) op[2 * DD] = scale * fmaf(sr, sr, si * si);
        STEP(cur.w) op[3 * DD] = scale * fmaf(sr, sr, si * si);
        op += 4 * DD;
        cur = nxt;
    }
    // Last group (no prefetch).
    STEP(cur.x) op[0 * DD] = scale * fmaf(sr, sr, si * si);
    STEP(cur.y) op[1 * DD] = scale * fmaf(sr, sr, si * si);
    STEP(cur.z) op[2 * DD] = scale * fmaf(sr, sr, si * si);
    STEP(cur.w) op[3 * DD] = scale * fmaf(sr, sr, si * si);
}

extern "C" void kernel_launch(void* const* d_in, const int* in_sizes, int n_in,
                              void* d_out, int out_size, void* d_ws, size_t ws_size,
                              hipStream_t stream) {
    const float* x         = (const float*)d_in[0];
    const float* omega     = (const float*)d_in[1];
    const float* alpha_raw = (const float*)d_in[2];
    const float* b_log_mag = (const float*)d_in[3];
    // d_in[4] = b_phase: unused (cancels in |H|^2)
    const int*   Kp        = (const int*)d_in[5];
    float* out = (float*)d_out;

    dim3 grid(NCHUNK, BB);
    dim3 block(DD);
    sstfr_kernel<<<grid, block, 0, stream>>>(x, omega, alpha_raw, b_log_mag, Kp, out);
}